// Round 5
// baseline (177.501 us; speedup 1.0000x reference)
//
#include <hip/hip_runtime.h>

// Involution2d: B=8, C=256, G=4 (Cpg=64), H=W=Ho=Wo=64, K=7, PAD=3, STRIDE=1.
// out[b, g*64+c, y, x] = sum_{kh,kw} in[b, g*64+c, y+kh-3, x+kw-3] * w[b,g,kh,kw,y,x] + bias[g*64+c]
//
// R5: fix R4's exposed weight-load latency (VGPR=40 proved the compiler
// serialized load->16FMA->load; VALUBusy 29%, nothing saturated).
//  - EXPLICIT ping-pong software pipeline on weight tap-rows: real kh+=2
//    loop, W1 loads issue before W0 compute and vice versa -> ~1 full
//    compute block (~400 cyc) of latency cover per load batch.
//  - __launch_bounds__(128,2): ~175-reg live set (W0+W1=112 + acc 32 +
//    window 14) must NOT be squeezed -- tight caps made the compiler
//    serialize in R1/R2/R4.
//  - x-widen: 8 px/thread -> 7 ds_read2 serve 112 FMAs (was 5 per 28).
//  - column-per-thread staging (fixed col, loop rows): pure add addressing,
//    no div/mod per element.

#define TX 8            // x-threads, 8 px each -> 64 px
#define TYB 16          // y rows per block
#define NTHR (TX * TYB) // 128
#define NC 4            // channels per block
#define STG_ROWS 22     // 16 + 6 halo
#define STG_COLS 70     // 64 + 6 halo
#define LDS_STRIDE 71   // odd: rows rotate across mod-4 dword-bank classes

__global__ __launch_bounds__(NTHR, 2)   // cap 256 VGPR: room for the pipeline
void involution_kernel(const float* __restrict__ in,
                       const float* __restrict__ w,
                       const float* __restrict__ bias,
                       float* __restrict__ out) {
    __shared__ float lds[NC * STG_ROWS * LDS_STRIDE];   // 24992 B

    const int tx = threadIdx.x;      // 0..7
    const int ty = threadIdx.y;      // 0..15
    const int tid = ty * TX + tx;
    const int x0 = tx * 8;
    const int Y0 = blockIdx.x * TYB;
    const int y  = Y0 + ty;
    const int c0 = blockIdx.y * NC;
    const int bz = blockIdx.z;       // b*4 + g
    const int g  = bz & 3;

    const float* inb = in + (size_t)bz * 64 * 4096 + (size_t)c0 * 4096;

    // ---- staging: thread owns one column, loops rows (add-only addressing) ----
    if (tid < STG_COLS) {
        const int col = tid;
        const int gx  = col - 3;
        const bool xok = (gx >= 0) && (gx < 64);
        #pragma unroll 1
        for (int ci = 0; ci < NC; ++ci) {
            const float* p  = inb + ci * 4096 + gx;
            float*       lp = &lds[ci * STG_ROWS * LDS_STRIDE + col];
            #pragma unroll
            for (int rr = 0; rr < STG_ROWS; ++rr) {
                int gy = Y0 + rr - 3;
                float v = 0.f;
                if (xok && gy >= 0 && gy < 64) v = p[gy * 64];
                lp[rr * LDS_STRIDE] = v;
            }
        }
    }
    __syncthreads();

    float acc[NC][8];
    #pragma unroll
    for (int ci = 0; ci < NC; ++ci)
        #pragma unroll
        for (int e = 0; e < 8; ++e) acc[ci][e] = 0.f;

    const float* wb = w + (size_t)bz * 49 * 4096 + y * 64 + x0;

    float4 W0[2][7], W1[2][7];   // [x-quad][kw] for one tap row

    auto loadrow = [&](int kh, float4 (&W)[2][7]) {
        #pragma unroll
        for (int kw = 0; kw < 7; ++kw) {
            const float* p = wb + (size_t)(kh * 7 + kw) * 4096;
            W[0][kw] = *(const float4*)p;
            W[1][kw] = *(const float4*)(p + 4);
        }
    };
    auto comprow = [&](int kh, const float4 (&W)[2][7]) {
        #pragma unroll
        for (int ci = 0; ci < NC; ++ci) {
            const float* lr = &lds[(ci * STG_ROWS + ty + kh) * LDS_STRIDE + x0];
            float v[14];
            #pragma unroll
            for (int j = 0; j < 14; ++j) v[j] = lr[j];
            #pragma unroll
            for (int kw = 0; kw < 7; ++kw) {
                #pragma unroll
                for (int q = 0; q < 2; ++q) {
                    const float4 wv = W[q][kw];
                    acc[ci][q * 4 + 0] += v[4 * q + 0 + kw] * wv.x;
                    acc[ci][q * 4 + 1] += v[4 * q + 1 + kw] * wv.y;
                    acc[ci][q * 4 + 2] += v[4 * q + 2 + kw] * wv.z;
                    acc[ci][q * 4 + 3] += v[4 * q + 3 + kw] * wv.w;
                }
            }
        }
    };

    // ---- ping-pong pipeline over the 7 tap rows ----
    loadrow(0, W0);
    #pragma unroll 1                 // real loop: blocks hoist-all (R1 failure)
    for (int kh = 0; kh < 6; kh += 2) {   // kh = 0, 2, 4
        loadrow(kh + 1, W1);         // in flight during comprow(kh)
        comprow(kh, W0);
        loadrow(kh + 2, W0);         // kh+2 = 2,4,6 (always valid)
        comprow(kh + 1, W1);
    }
    comprow(6, W0);

    // ---- epilogue ----
    float* outb = out + (size_t)bz * 64 * 4096 + (size_t)c0 * 4096 + y * 64 + x0;
    #pragma unroll
    for (int ci = 0; ci < NC; ++ci) {
        const float bv = bias[g * 64 + c0 + ci];
        float4 o0, o1;
        o0.x = acc[ci][0] + bv; o0.y = acc[ci][1] + bv;
        o0.z = acc[ci][2] + bv; o0.w = acc[ci][3] + bv;
        o1.x = acc[ci][4] + bv; o1.y = acc[ci][5] + bv;
        o1.z = acc[ci][6] + bv; o1.w = acc[ci][7] + bv;
        *(float4*)(outb + (size_t)ci * 4096)     = o0;
        *(float4*)(outb + (size_t)ci * 4096 + 4) = o1;
    }
}

extern "C" void kernel_launch(void* const* d_in, const int* in_sizes, int n_in,
                              void* d_out, int out_size, void* d_ws, size_t ws_size,
                              hipStream_t stream) {
    const float* in   = (const float*)d_in[0];  // (8,256,64,64)
    const float* wgt  = (const float*)d_in[1];  // (8,4,7,7,64,64)
    const float* bias = (const float*)d_in[2];  // (256,)
    float* out = (float*)d_out;                 // (8,256,64,64)

    dim3 block(TX, TYB, 1);                     // 128 threads
    dim3 grid(64 / TYB, 64 / NC, 32);           // (4, 16, 32) = 2048 blocks
    involution_kernel<<<grid, block, 0, stream>>>(in, wgt, bias, out);
}

// Round 6
// 130.802 us; speedup vs baseline: 1.3570x; 1.3570x over previous
//
#include <hip/hip_runtime.h>

// Involution2d: B=8, C=256, G=4 (Cpg=64), H=W=Ho=Wo=64, K=7, PAD=3, STRIDE=1.
// out[b, g*64+c, y, x] = sum_{kh,kw} in[b, g*64+c, y+kh-3, x+kw-3] * w[b,g,kh,kw,y,x] + bias[g*64+c]
//
// R6: RESIDENT weights via kh-split across lane halves.
//  Evidence R1/R2/R4/R5: compiler refuses >~110 VGPRs of in-flight global
//  data in a loop; streaming weights from L3 (411 MB at NC=4) is the
//  structural bottleneck (R4 60us, VALUBusy 29%, nothing saturated).
//  Fix: weights loaded ONCE per thread before the channel loop.
//   - px=4, 7 kh rows split across wave halves: lanes 0-31 take kh 0..3,
//     lanes 32-63 take kh 3..6 (kh=3 taps zeroed) -> 28 float4 = 112 regs.
//   - 32-channel loop; partial sums merged with one __shfl_xor(32) per
//     component; lanes<32 store. Weight tensor traffic: 25.7MB x2 total.
//   - input: single-channel 10x71 tile (2.8KB LDS), register-prefetch
//     double-stage per channel; staging guards/offsets precomputed once.
//  Go/no-go: VGPR_Count >= 140 means W stayed resident.

#define NTHR 128
#define TILE_Y 4
#define NCH 32
#define STG_ROWS 10          // TILE_Y + 6 halo
#define STG_COLS 70          // 64 + 6 halo
#define LDS_STRIDE 71        // odd: rows rotate across mod-4 dword-bank classes
#define STG_N (STG_ROWS * STG_COLS)        // 700
#define NSTG ((STG_N + NTHR - 1) / NTHR)   // 6

__global__ __launch_bounds__(NTHR, 2)
void involution_kernel(const float* __restrict__ in,
                       const float* __restrict__ w,
                       const float* __restrict__ bias,
                       float* __restrict__ out) {
    __shared__ float lds[STG_ROWS * LDS_STRIDE];   // 2840 B

    const int tid  = threadIdx.x;
    const int lane = tid & 63;
    const int wv   = tid >> 6;          // 0..1 (2 waves)
    const int half = lane >> 5;         // 0: kh 0..3, 1: kh 3..6
    const int sub  = lane & 31;
    const int q    = sub & 15;          // x-quad
    const int r    = (sub >> 4) | (wv << 1);   // 0..3: output row in tile
    const int x0   = q * 4;
    const int Y0   = blockIdx.x * TILE_Y;
    const int y    = Y0 + r;
    const int c0   = blockIdx.y * NCH;
    const int bz   = blockIdx.z;        // b*4 + g
    const int g    = bz & 3;
    const int khb  = half ? 3 : 0;

    // ---- weight prologue: 28 float4 per thread, resident for the whole kernel ----
    float4 W[28];
    const float* wb = w + (size_t)bz * 49 * 4096 + y * 64 + x0;
    #pragma unroll
    for (int k = 0; k < 28; ++k) {
        const int kh = khb + k / 7;
        const int kw = k % 7;
        float4 v = make_float4(0.f, 0.f, 0.f, 0.f);
        if (half == 0 || k >= 7)   // half1 zeroes its kh=3 row (half0 owns it)
            v = *(const float4*)(wb + (size_t)(kh * 7 + kw) * 4096);
        W[k] = v;
    }

    // ---- precompute per-thread staging slots (guards identical every channel) ----
    int goff[NSTG];    // input-plane offset, or -1 (zero/skip)
    int laddr[NSTG];   // lds dword address, or -1 (skip)
    #pragma unroll
    for (int j = 0; j < NSTG; ++j) {
        const int i = tid + j * NTHR;
        goff[j] = -1; laddr[j] = -1;
        if (i < STG_N) {
            const int rr = i / STG_COLS;
            const int cc = i - rr * STG_COLS;
            laddr[j] = rr * LDS_STRIDE + cc;
            const int gy = Y0 + rr - 3;
            const int gx = cc - 3;
            if (gy >= 0 && gy < 64 && gx >= 0 && gx < 64)
                goff[j] = gy * 64 + gx;
        }
    }

    const float* inb  = in  + (size_t)bz * 64 * 4096 + (size_t)c0 * 4096;
    float*       outb = out + (size_t)bz * 64 * 4096 + (size_t)c0 * 4096 + y * 64 + x0;
    const float* bias_g = bias + g * 64 + c0;

    // ---- stage channel 0 ----
    #pragma unroll
    for (int j = 0; j < NSTG; ++j) {
        if (laddr[j] >= 0)
            lds[laddr[j]] = (goff[j] >= 0) ? inb[goff[j]] : 0.f;
    }
    __syncthreads();

    #pragma unroll 1
    for (int c = 0; c < NCH; ++c) {
        // prefetch next channel into registers (in flight during compute)
        float pf[NSTG];
        const float* pc = inb + (size_t)(c + 1) * 4096;
        if (c + 1 < NCH) {
            #pragma unroll
            for (int j = 0; j < NSTG; ++j)
                pf[j] = (goff[j] >= 0) ? pc[goff[j]] : 0.f;
        }

        // compute: 4 tap-rows, 7 kw, 4 px -> 112 FMAs from resident W
        float acc0 = 0.f, acc1 = 0.f, acc2 = 0.f, acc3 = 0.f;
        #pragma unroll
        for (int j = 0; j < 4; ++j) {
            const float* lr = &lds[(r + khb + j) * LDS_STRIDE + x0];
            float v[10];
            #pragma unroll
            for (int d = 0; d < 10; ++d) v[d] = lr[d];
            #pragma unroll
            for (int kw = 0; kw < 7; ++kw) {
                const float4 wv4 = W[j * 7 + kw];
                acc0 += v[kw + 0] * wv4.x;
                acc1 += v[kw + 1] * wv4.y;
                acc2 += v[kw + 2] * wv4.z;
                acc3 += v[kw + 3] * wv4.w;
            }
        }

        // merge kh-halves (lane L <-> L^32), then lanes<32 store
        acc0 += __shfl_xor(acc0, 32);
        acc1 += __shfl_xor(acc1, 32);
        acc2 += __shfl_xor(acc2, 32);
        acc3 += __shfl_xor(acc3, 32);

        const float bv = bias_g[c];    // wave-uniform, before the divergent store
        if (half == 0) {
            float4 o;
            o.x = acc0 + bv; o.y = acc1 + bv; o.z = acc2 + bv; o.w = acc3 + bv;
            *(float4*)(outb + (size_t)c * 4096) = o;
        }

        if (c + 1 < NCH) {
            __syncthreads();           // everyone done reading tile c
            #pragma unroll
            for (int j = 0; j < NSTG; ++j)
                if (laddr[j] >= 0) lds[laddr[j]] = pf[j];
            __syncthreads();           // tile c+1 visible
        }
    }
}

extern "C" void kernel_launch(void* const* d_in, const int* in_sizes, int n_in,
                              void* d_out, int out_size, void* d_ws, size_t ws_size,
                              hipStream_t stream) {
    const float* in   = (const float*)d_in[0];  // (8,256,64,64)
    const float* wgt  = (const float*)d_in[1];  // (8,4,7,7,64,64)
    const float* bias = (const float*)d_in[2];  // (256,)
    float* out = (float*)d_out;                 // (8,256,64,64)

    dim3 block(NTHR, 1, 1);                     // 128 threads
    dim3 grid(64 / TILE_Y, 64 / NCH, 32);       // (16, 2, 32) = 1024 blocks
    involution_kernel<<<grid, block, 0, stream>>>(in, wgt, bias, out);
}